// Round 1
// baseline (361.118 us; speedup 1.0000x reference)
//
#include <hip/hip_runtime.h>
#include <hip/hip_bf16.h>
#include <stdint.h>

// Problem constants (B,S,D,H fixed by the reference)
constexpr int kB  = 4;
constexpr int kS  = 2048;
constexpr int kD  = 1024;
constexpr int kH  = 16;
constexpr int kDH = 64;
constexpr int kM  = kB * kS;     // 8192
constexpr int k3D = 3 * kD;      // 3072

// 0.125 (1/sqrt(DH)) * log2(e): scores leave GEMM1 in log2 domain -> exp2
constexpr float kQscale = 0.18033688011112042f;

typedef __attribute__((ext_vector_type(8))) short short8;  // 8 bf16 (4 VGPRs)
typedef __attribute__((ext_vector_type(4))) float f32x4;   // MFMA C/D

__device__ __forceinline__ float exp2v(float x) {
  return __builtin_amdgcn_exp2f(x);   // v_exp_f32 (base-2)
}

__device__ __forceinline__ unsigned short f2bf(float f) {
  unsigned u = __float_as_uint(f);
  u += 0x7fffu + ((u >> 16) & 1u);   // RNE
  return (unsigned short)(u >> 16);
}
__device__ __forceinline__ unsigned pack2bf(float a, float b) {
  return (unsigned)f2bf(a) | ((unsigned)f2bf(b) << 16);
}

// async global->LDS, 16B per lane. LDS dest must be wave-uniform base + lane*16.
__device__ __forceinline__ void async16(const void* g, void* l) {
  __builtin_amdgcn_global_load_lds(
      (const __attribute__((address_space(1))) unsigned int*)g,
      (__attribute__((address_space(3))) unsigned int*)l, 16, 0, 0);
}

// ---------------------------------------------------------------------------
// fp32 -> bf16 convert for all three inputs in one launch
// ---------------------------------------------------------------------------
__global__ __launch_bounds__(256) void cvt_bf16_3(
    const float* __restrict__ x, const float* __restrict__ wi,
    const float* __restrict__ wo, unsigned short* __restrict__ xb,
    unsigned short* __restrict__ wib, unsigned short* __restrict__ wob) {
  constexpr int n_x  = kM * kD / 4;
  constexpr int n_wi = k3D * kD / 4;
  int i = blockIdx.x * 256 + threadIdx.x;
  const float* src;
  unsigned short* dst;
  int j;
  if (i < n_x)            { src = x;  dst = xb;  j = i; }
  else if (i < n_x + n_wi){ src = wi; dst = wib; j = i - n_x; }
  else                    { src = wo; dst = wob; j = i - n_x - n_wi; }
  float4 v = ((const float4*)src)[j];
  ushort4 r;
  r.x = f2bf(v.x); r.y = f2bf(v.y); r.z = f2bf(v.z); r.w = f2bf(v.w);
  ((ushort4*)dst)[j] = r;
}

// ---------------------------------------------------------------------------
// MFMA GEMM: C[M][N] = A[M][K](bf16) @ Bt[N][K](bf16)^T + bias (fp32 acc).
// 128xBN tile (BN=256), BK=32, 4 waves 2Mx2N (per-wave 64 x BN/2),
// double-buffered LDS (48 KB -> 2 blocks/CU), one barrier/K-iter.
// Intensity: 87 FLOP/staged-byte (vs 65 at 128x128); 32 MFMA/wave/iter gives
// the prefetch 2x the compute window. XCD-swizzled block ids: each XCD owns
// 8 consecutive A-panel rows x all x-tiles -> A-panels L2-resident.
// QSCALE: multiply (acc+bias) by kQscale for output cols < kD (Q columns).
// ---------------------------------------------------------------------------
template <int BN, bool OUT_BF16, bool QSCALE>
__global__ __launch_bounds__(256, 2) void gemm_mfma(
    const unsigned short* __restrict__ A, int lda,
    const unsigned short* __restrict__ Bt, int ldb,
    const float* __restrict__ bias, void* __restrict__ Cp, int ldc, int K) {
  constexpr int BM = 128;
  constexpr int NT = BN / 32;   // per-wave n-fragments (BN/2 cols / 16)
  constexpr int CA = BM / 64;   // A chunks staged per thread (2)
  constexpr int CB = BN / 64;   // B chunks staged per thread (4)
  __shared__ unsigned short As[2][BM * 32];  // [kc 0..3][row 0..BM-1][8]
  __shared__ unsigned short Bs[2][BN * 32];  // [kc 0..3][col 0..BN-1][8]
  const int t = threadIdx.x;
  const int lane = t & 63, l15 = lane & 15, quad = lane >> 4, w = t >> 6;

  // Bijective XCD swizzle (both call sites have nwg % 8 == 0; guarded anyway)
  const int nwg = gridDim.x * gridDim.y;
  int bid = blockIdx.y * gridDim.x + blockIdx.x;
  if ((nwg & 7) == 0) bid = (bid & 7) * (nwg >> 3) + (bid >> 3);
  const int bx = bid % gridDim.x, by = bid / gridDim.x;

  const int row0 = by * BM, col0 = bx * BN;
  const int wm = (w & 1) * 64, wn = (w >> 1) * (BN / 2);

  f32x4 acc[4][NT] = {};

  // chunk q = t + j*256: A chunk -> (kc = q/BM, row = q%BM), 8 shorts;
  // LDS dest is linear q*16B (wave-uniform base + lane*16 for gload_lds).
  const unsigned short* ga[CA];
  const unsigned short* gb[CB];
#pragma unroll
  for (int j = 0; j < CA; ++j) {
    const int q = t + j * 256;
    ga[j] = A + (size_t)(row0 + (q & (BM - 1))) * lda + (q / BM) * 8;
  }
#pragma unroll
  for (int j = 0; j < CB; ++j) {
    const int q = t + j * 256;
    gb[j] = Bt + (size_t)(col0 + (q & (BN - 1))) * ldb + (q / BN) * 8;
  }

  const int nIter = K / 32;
#pragma unroll
  for (int j = 0; j < CA; ++j) async16(ga[j], As[0] + (t + j * 256) * 8);
#pragma unroll
  for (int j = 0; j < CB; ++j) async16(gb[j], Bs[0] + (t + j * 256) * 8);

  for (int it = 0; it < nIter; ++it) {
    __syncthreads();  // drains tile 'it' staging (issued a full iter ago)
    const int cb = it & 1, nb = cb ^ 1;
    if (it + 1 < nIter) {
      const int k0 = (it + 1) * 32;
#pragma unroll
      for (int j = 0; j < CA; ++j)
        async16(ga[j] + k0, As[nb] + (t + j * 256) * 8);
#pragma unroll
      for (int j = 0; j < CB; ++j)
        async16(gb[j] + k0, Bs[nb] + (t + j * 256) * 8);
    }
    short8 af[4], bf[NT];
#pragma unroll
    for (int mt = 0; mt < 4; ++mt)
      af[mt] = *(const short8*)(As[cb] + (quad * BM + wm + mt * 16 + l15) * 8);
#pragma unroll
    for (int nt = 0; nt < NT; ++nt)
      bf[nt] = *(const short8*)(Bs[cb] + (quad * BN + wn + nt * 16 + l15) * 8);
#pragma unroll
    for (int mt = 0; mt < 4; ++mt)
#pragma unroll
      for (int nt = 0; nt < NT; ++nt)
        acc[mt][nt] = __builtin_amdgcn_mfma_f32_16x16x32_bf16(
            af[mt], bf[nt], acc[mt][nt], 0, 0, 0);
  }

  const float sc = (QSCALE && col0 < kD) ? kQscale : 1.0f;
  float bv[NT];
#pragma unroll
  for (int nt = 0; nt < NT; ++nt) bv[nt] = bias[col0 + wn + nt * 16 + l15];
#pragma unroll
  for (int mt = 0; mt < 4; ++mt)
#pragma unroll
    for (int i = 0; i < 4; ++i) {
      const size_t r = (size_t)(row0 + wm + mt * 16 + quad * 4 + i);
#pragma unroll
      for (int nt = 0; nt < NT; ++nt) {
        float v = (acc[mt][nt][i] + bv[nt]) * sc;
        const size_t cidx = r * (size_t)ldc + col0 + wn + nt * 16 + l15;
        if (OUT_BF16) ((unsigned short*)Cp)[cidx] = f2bf(v);
        else          ((float*)Cp)[cidx] = v;
      }
    }
}

// ---------------------------------------------------------------------------
// V transpose: qkvb V-slots [b*S+s][2048 + h*64 + d] -> vtb [(b*16+h)*64+d][s]
// ---------------------------------------------------------------------------
__global__ __launch_bounds__(256) void v_transpose(
    const unsigned short* __restrict__ qkvb, unsigned short* __restrict__ vtb) {
  __shared__ unsigned short L[64][72];  // +8 pad: 16B-aligned rows
  const int kt = blockIdx.x, h = blockIdx.y, b = blockIdx.z;
  const int t = threadIdx.x;
  const unsigned short* src = qkvb + (size_t)(b * kS) * k3D + 2 * kD + h * kDH;
#pragma unroll
  for (int p = 0; p < 2; ++p) {
    const int q = t + p * 256;
    const int r = q >> 3, c = q & 7;
    *(short8*)(&L[r][c * 8]) =
        *(const short8*)(src + (size_t)(kt * 64 + r) * k3D + c * 8);
  }
  __syncthreads();
  unsigned short* dst = vtb + (size_t)((b * kH + h) * kDH) * kS + kt * 64;
  const int key2 = (t & 31) * 2, dg = t >> 5;
#pragma unroll
  for (int i = 0; i < 8; ++i) {
    const int d = dg * 8 + i;
    ushort2 v = make_ushort2(L[key2][d], L[key2 + 1][d]);
    *(ushort2*)(dst + (size_t)d * kS + key2) = v;  // coalesced along keys
  }
}

// ---------------------------------------------------------------------------
// MFMA flash attention, S^T formulation, register-Q, pipelined staging,
// COMPLEMENTARY-PAIR BALANCED: block = (b, h, pair p) handles q-tiles p and
// 31-p (64 rows each). Causal work = (p+1) + (32-p) = 33 k-tiles for EVERY
// block -> zero tail, 4 blocks/CU (16 waves) sustained for the whole kernel.
// 24 KB LDS. 4 waves x 16 q-rows per q-tile.
// ---------------------------------------------------------------------------
__global__ __launch_bounds__(256, 4) void flash_attn_mfma(
    unsigned short* __restrict__ qkvb, const unsigned short* __restrict__ vtb,
    const int* __restrict__ cflag) {
  __shared__ unsigned short QP[4096];  // Q then P: [chunk 0..7][q 0..63][8] 8 KB
  __shared__ unsigned short Ks[4096];  // [dchunk 0..7][key 0..63][8]        8 KB
  __shared__ unsigned short Vt[4096];  // [keychunk 0..7][d 0..63][8]        8 KB

  const int pr = blockIdx.x;           // pair id 0..15
  const int h = blockIdx.y, b = blockIdx.z;
  const int t = threadIdx.x;
  const int lane = t & 63, l15 = lane & 15, quad = lane >> 4, w = t >> 6;
  const bool causal = (*cflag) != 0;

  unsigned short* qbase = qkvb + (size_t)(b * kS) * k3D + h * kDH;
  const unsigned short* vbase = vtb + (size_t)((b * kH + h) * kDH) * kS;
  const int c0 = t, c1 = t + 256;

  for (int half = 0; half < 2; ++half) {
    const int qt = half ? (31 - pr) : pr;
    const int q0 = qt * 64;
    const int ntiles = causal ? (qt + 1) : 32;

    // ---- prologue: stage Q (512 chunks) + K tile 0
    // (safe vs previous half: its last B_end ordered all LDS reads before this)
    async16(qbase + (size_t)(q0 + (c0 & 63)) * k3D + (c0 >> 6) * 8, QP + c0 * 8);
    async16(qbase + (size_t)(q0 + (c1 & 63)) * k3D + (c1 >> 6) * 8, QP + c1 * 8);
    async16(qbase + kD + (size_t)(c0 & 63) * k3D + (c0 >> 6) * 8, Ks + c0 * 8);
    async16(qbase + kD + (size_t)(c1 & 63) * k3D + (c1 >> 6) * 8, Ks + c1 * 8);
    __syncthreads();  // drains Q + K0

    // hoist Q fragments to registers — QP becomes the P buffer afterwards
    short8 bq[2];
#pragma unroll
    for (int kf = 0; kf < 2; ++kf)
      bq[kf] = *(const short8*)(
          QP + ((kf * 4 + quad) * 64 + w * 16 + l15) * 8);

    // V tile 0 (in flight across QK^T(0); drained at B_mid(0))
    async16(vbase + (size_t)(c0 & 63) * kS + (c0 >> 6) * 8, Vt + c0 * 8);
    async16(vbase + (size_t)(c1 & 63) * kS + (c1 >> 6) * 8, Vt + c1 * 8);

    f32x4 O[4] = {};                  // [d-tile ntd]; q row = w*16+quad*4+i
    float m_i = -3.0e38f, l_i = 0.f;  // per q (q = w*16+l15)

    for (int kt = 0; kt < ntiles; ++kt) {
      const int kk0 = kt * 64;

      // ---- S^T = K·Q^T: key = kk0+mt*16+quad*4+reg, q = w*16+l15
      f32x4 s[4];
#pragma unroll
      for (int mt = 0; mt < 4; ++mt) {
        short8 a0 = *(const short8*)(Ks + ((quad)*64 + mt * 16 + l15) * 8);
        short8 a1 = *(const short8*)(Ks + ((4 + quad) * 64 + mt * 16 + l15) * 8);
        f32x4 z = {};
        z = __builtin_amdgcn_mfma_f32_16x16x32_bf16(a0, bq[0], z, 0, 0, 0);
        z = __builtin_amdgcn_mfma_f32_16x16x32_bf16(a1, bq[1], z, 0, 0, 0);
        s[mt] = z;
      }

      __syncthreads();  // B_mid: drains V(kt); all QK^T reads of Ks complete

      // issue K(kt+1) — in flight across softmax + PV, drained at B_end
      if (kt + 1 < ntiles) {
        const int kn = kk0 + 64;
        async16(qbase + kD + (size_t)(kn + (c0 & 63)) * k3D + (c0 >> 6) * 8,
                Ks + c0 * 8);
        async16(qbase + kD + (size_t)(kn + (c1 & 63)) * k3D + (c1 >> 6) * 8,
                Ks + c1 * 8);
      }

      // ---- online softmax (scores in log2 domain; diagonal tile masked)
      const int gq = q0 + w * 16 + l15;
      if (causal && kt == ntiles - 1) {
#pragma unroll
        for (int mt = 0; mt < 4; ++mt)
#pragma unroll
          for (int i = 0; i < 4; ++i)
            if (kk0 + mt * 16 + quad * 4 + i > gq) s[mt][i] = -3.0e38f;
      }
      float mx = -3.0e38f;
#pragma unroll
      for (int mt = 0; mt < 4; ++mt)
#pragma unroll
        for (int i = 0; i < 4; ++i) mx = fmaxf(mx, s[mt][i]);
      mx = fmaxf(mx, __shfl_xor(mx, 16));
      mx = fmaxf(mx, __shfl_xor(mx, 32));
      const float mn = fmaxf(m_i, mx);
      const float alpha = exp2v(m_i - mn);
      m_i = mn;

      float p[4][4];
      float rs = 0.f;
#pragma unroll
      for (int mt = 0; mt < 4; ++mt)
#pragma unroll
        for (int i = 0; i < 4; ++i) {
          p[mt][i] = exp2v(s[mt][i] - mn);
          rs += p[mt][i];
        }
      rs += __shfl_xor(rs, 16);
      rs += __shfl_xor(rs, 32);
      l_i = l_i * alpha + rs;

      // packed P store: 4 consecutive keys (mt*16+quad*4 .. +3) at row gq
#pragma unroll
      for (int mt = 0; mt < 4; ++mt) {
        uint2 pk = make_uint2(pack2bf(p[mt][0], p[mt][1]),
                              pack2bf(p[mt][2], p[mt][3]));
        *(uint2*)(QP + ((mt * 2 + (quad >> 1)) * 64 + w * 16 + l15) * 8 +
                  (quad & 1) * 4) = pk;
      }

      // ---- rescale O by alpha of its own q-row (row = w*16 + quad*4 + i)
#pragma unroll
      for (int i = 0; i < 4; ++i) {
        const float a = __shfl(alpha, quad * 4 + i);
#pragma unroll
        for (int ntd = 0; ntd < 4; ++ntd) O[ntd][i] *= a;
      }

      // ---- O += P·V (P rows wave-private; Vt drained at B_mid)
#pragma unroll
      for (int kf = 0; kf < 2; ++kf) {
        short8 aP = *(const short8*)(
            QP + ((kf * 4 + quad) * 64 + w * 16 + l15) * 8);
#pragma unroll
        for (int ntd = 0; ntd < 4; ++ntd) {
          short8 bV = *(const short8*)(
              Vt + ((kf * 4 + quad) * 64 + ntd * 16 + l15) * 8);
          O[ntd] = __builtin_amdgcn_mfma_f32_16x16x32_bf16(
              aP, bV, O[ntd], 0, 0, 0);
        }
      }

      __syncthreads();  // B_end: drains K(kt+1); all PV reads of Vt/QP complete

      // issue V(kt+1) — in flight across next QK^T + softmax
      if (kt + 1 < ntiles) {
        const int kn = kk0 + 64;
        async16(vbase + (size_t)(c0 & 63) * kS + kn + (c0 >> 6) * 8, Vt + c0 * 8);
        async16(vbase + (size_t)(c1 & 63) * kS + kn + (c1 >> 6) * 8, Vt + c1 * 8);
      }
    }

    // ---- epilogue: /l, bf16, overwrite own Q slots
#pragma unroll
    for (int i = 0; i < 4; ++i) {
      const float linv = 1.0f / __shfl(l_i, quad * 4 + i);
      unsigned short* dst =
          qbase + (size_t)(q0 + w * 16 + quad * 4 + i) * k3D;
#pragma unroll
      for (int ntd = 0; ntd < 4; ++ntd)
        dst[ntd * 16 + l15] = f2bf(O[ntd][i] * linv);
    }
  }
}

// ---------------------------------------------------------------------------
extern "C" void kernel_launch(void* const* d_in, const int* in_sizes, int n_in,
                              void* d_out, int out_size, void* d_ws,
                              size_t ws_size, hipStream_t stream) {
  const float* x     = (const float*)d_in[0];
  const float* w_in  = (const float*)d_in[1];
  const float* b_in  = (const float*)d_in[2];
  const float* w_out = (const float*)d_in[3];
  const float* b_out = (const float*)d_in[4];
  const int*   cfl   = (const int*)d_in[5];
  float* out = (float*)d_out;

  // workspace layout (all 16B-aligned), total 92.3 MB
  char* ws = (char*)d_ws;
  unsigned short* qkvb = (unsigned short*)(ws);              // 8192x3072 bf16 = 48 MB
  unsigned short* xb   = (unsigned short*)(ws + 50331648);   // 8192x1024 bf16 = 16 MB
  unsigned short* wib  = (unsigned short*)(ws + 67108864);   // 3072x1024 bf16 =  6 MB
  unsigned short* wob  = (unsigned short*)(ws + 73400320);   // 1024x1024 bf16 =  2 MB
  unsigned short* vtb  = (unsigned short*)(ws + 75497472);   // [b,h,d,s] bf16 = 16 MB

  // 0) all three fp32->bf16 conversions in one launch
  cvt_bf16_3<<<(kM * kD + k3D * kD + kD * kD) / 4 / 256, 256, 0, stream>>>(
      x, w_in, w_out, xb, wib, wob);

  // 1) qkv = x @ w_in^T + b_in (bf16 out; Q cols pre-scaled by 0.125*log2e)
  //    128x256 tile: grid 12x64 = 768 blocks (3 clean rounds at 2 blocks/CU)
  gemm_mfma<256, true, true><<<dim3(k3D / 256, kM / 128), 256, 0, stream>>>(
      xb, kD, wib, kD, b_in, qkvb, k3D, kD);

  // 2) V transpose for PV staging
  v_transpose<<<dim3(kS / 64, kH, kB), 256, 0, stream>>>(qkvb, vtb);

  // 3) flash attention (pair-balanced, bf16 MFMA, register-Q, pipelined)
  flash_attn_mfma<<<dim3(16, kH, kB), 256, 0, stream>>>(qkvb, vtb, cfl);

  // 4) out = attn @ w_out^T + b_out (fp32 out; A rows inside qkvb, lda=3072)
  //    128x256 tile: grid 4x64 = 256 blocks
  gemm_mfma<256, false, false><<<dim3(kD / 256, kM / 128), 256, 0, stream>>>(
      qkvb, k3D, wob, kD, b_out, out, kD, kD);
}

// Round 2
// 349.106 us; speedup vs baseline: 1.0344x; 1.0344x over previous
//
#include <hip/hip_runtime.h>
#include <hip/hip_bf16.h>
#include <stdint.h>

// Problem constants (B,S,D,H fixed by the reference)
constexpr int kB  = 4;
constexpr int kS  = 2048;
constexpr int kD  = 1024;
constexpr int kH  = 16;
constexpr int kDH = 64;
constexpr int kM  = kB * kS;     // 8192
constexpr int k3D = 3 * kD;      // 3072

// 0.125 (1/sqrt(DH)) * log2(e): scores leave GEMM1 in log2 domain -> exp2
constexpr float kQscale = 0.18033688011112042f;

typedef __attribute__((ext_vector_type(8))) short short8;  // 8 bf16 (4 VGPRs)
typedef __attribute__((ext_vector_type(4))) float f32x4;   // MFMA C/D

__device__ __forceinline__ float exp2v(float x) {
  return __builtin_amdgcn_exp2f(x);   // v_exp_f32 (base-2)
}

__device__ __forceinline__ unsigned short f2bf(float f) {
  unsigned u = __float_as_uint(f);
  u += 0x7fffu + ((u >> 16) & 1u);   // RNE
  return (unsigned short)(u >> 16);
}
__device__ __forceinline__ unsigned pack2bf(float a, float b) {
  return (unsigned)f2bf(a) | ((unsigned)f2bf(b) << 16);
}

// async global->LDS, 16B per lane. LDS dest must be wave-uniform base + lane*16.
__device__ __forceinline__ void async16(const void* g, void* l) {
  __builtin_amdgcn_global_load_lds(
      (const __attribute__((address_space(1))) unsigned int*)g,
      (__attribute__((address_space(3))) unsigned int*)l, 16, 0, 0);
}

// ---------------------------------------------------------------------------
// fp32 -> bf16 convert for all three inputs in one launch
// ---------------------------------------------------------------------------
__global__ __launch_bounds__(256) void cvt_bf16_3(
    const float* __restrict__ x, const float* __restrict__ wi,
    const float* __restrict__ wo, unsigned short* __restrict__ xb,
    unsigned short* __restrict__ wib, unsigned short* __restrict__ wob) {
  constexpr int n_x  = kM * kD / 4;
  constexpr int n_wi = k3D * kD / 4;
  int i = blockIdx.x * 256 + threadIdx.x;
  const float* src;
  unsigned short* dst;
  int j;
  if (i < n_x)            { src = x;  dst = xb;  j = i; }
  else if (i < n_x + n_wi){ src = wi; dst = wib; j = i - n_x; }
  else                    { src = wo; dst = wob; j = i - n_x - n_wi; }
  float4 v = ((const float4*)src)[j];
  ushort4 r;
  r.x = f2bf(v.x); r.y = f2bf(v.y); r.z = f2bf(v.z); r.w = f2bf(v.w);
  ((ushort4*)dst)[j] = r;
}

// ---------------------------------------------------------------------------
// MFMA GEMM: C[M][N] = A[M][K](bf16) @ Bt[N][K](bf16)^T + bias (fp32 acc).
// 128x128 tile, BK=32, 4 waves 2x2, chunk-major LDS (conflict-free, verified).
// T3/T4 counted-vmcnt pipeline: 3-buffer LDS ring, prefetch distance 2,
// s_waitcnt vmcnt(4) + raw s_barrier per iter (NEVER vmcnt(0) in main loop).
// Each staged tile gets ~2 iter-periods of latency cover instead of ~1 compute
// phase. T5 setprio(1) around the MFMA cluster. 48 KB LDS -> 3 blocks/CU.
// QSCALE: multiply (acc+bias) by kQscale for output cols < kD (Q columns).
// ---------------------------------------------------------------------------
template <bool OUT_BF16, bool QSCALE>
__global__ __launch_bounds__(256, 3) void gemm_mfma(
    const unsigned short* __restrict__ A, int lda,
    const unsigned short* __restrict__ Bt, int ldb,
    const float* __restrict__ bias, void* __restrict__ Cp, int ldc, int K) {
  __shared__ unsigned short As[3][4096];  // 24 KB: [kc8 0..3][row 0..127][8]
  __shared__ unsigned short Bs[3][4096];  // 24 KB
  const int t = threadIdx.x;
  const int lane = t & 63, l15 = lane & 15, quad = lane >> 4, w = t >> 6;

  // Bijective chunked XCD swizzle: XCD x owns logical bids [x*nwg/8, ...)
  // (consecutive by-rows x all bx -> A-panels + B working set per-XCD L2).
  const int nwg = gridDim.x * gridDim.y;
  int bid = blockIdx.y * gridDim.x + blockIdx.x;
  if ((nwg & 7) == 0) bid = (bid & 7) * (nwg >> 3) + (bid >> 3);
  const int bx = bid % gridDim.x, by = bid / gridDim.x;

  const int row0 = by * 128, col0 = bx * 128;
  const int wm = (w & 1) * 64, wn = (w >> 1) * 64;

  f32x4 acc[4][4] = {};

  const int q1 = t, q2 = t + 256;  // chunk ids; q = t keeps wave-contiguity
  const unsigned short* a1 = A  + (size_t)(row0 + (q1 & 127)) * lda + (q1 >> 7) * 8;
  const unsigned short* a2 = A  + (size_t)(row0 + (q2 & 127)) * lda + (q2 >> 7) * 8;
  const unsigned short* b1 = Bt + (size_t)(col0 + (q1 & 127)) * ldb + (q1 >> 7) * 8;
  const unsigned short* b2 = Bt + (size_t)(col0 + (q2 & 127)) * ldb + (q2 >> 7) * 8;

  const int nIter = K / 32;  // >= 2 required (K = 1024 here -> 32)

#define STAGE_TILE(tile, buf)                              \
  do {                                                     \
    const int k0_ = (tile) * 32;                           \
    async16(a1 + k0_, As[(buf)] + q1 * 8);                 \
    async16(a2 + k0_, As[(buf)] + q2 * 8);                 \
    async16(b1 + k0_, Bs[(buf)] + q1 * 8);                 \
    async16(b2 + k0_, Bs[(buf)] + q2 * 8);                 \
  } while (0)

  // prologue: tiles 0 and 1 in flight (8 outstanding loads per wave)
  STAGE_TILE(0, 0);
  STAGE_TILE(1, 1);

  for (int it = 0; it < nIter; ++it) {
    // Counted wait: drain tile 'it' (4 oldest loads), keep tile it+1 in
    // flight across the barrier. Only the last iteration drains fully.
    if (it + 1 < nIter) {
      asm volatile("s_waitcnt vmcnt(4)" ::: "memory");
    } else {
      asm volatile("s_waitcnt vmcnt(0)" ::: "memory");
    }
    __builtin_amdgcn_s_barrier();
    __builtin_amdgcn_sched_barrier(0);  // pin: no LDS reads above the barrier

    // stage tile it+2 into buf (it+2)%3 == (it-1)%3: all reads of that buf
    // (tile it-1) completed before the barrier above (every ds_read was
    // consumed by an MFMA issued pre-barrier).
    if (it + 2 < nIter) STAGE_TILE(it + 2, (it + 2) % 3);

    const unsigned short* as = As[it % 3];
    const unsigned short* bs = Bs[it % 3];
    short8 af[4], bf[4];
#pragma unroll
    for (int mt = 0; mt < 4; ++mt)
      af[mt] = *(const short8*)(as + (quad * 128 + wm + mt * 16 + l15) * 8);
#pragma unroll
    for (int nt = 0; nt < 4; ++nt)
      bf[nt] = *(const short8*)(bs + (quad * 128 + wn + nt * 16 + l15) * 8);

    __builtin_amdgcn_s_setprio(1);
#pragma unroll
    for (int mt = 0; mt < 4; ++mt)
#pragma unroll
      for (int nt = 0; nt < 4; ++nt)
        acc[mt][nt] = __builtin_amdgcn_mfma_f32_16x16x32_bf16(
            af[mt], bf[nt], acc[mt][nt], 0, 0, 0);
    __builtin_amdgcn_s_setprio(0);
  }
#undef STAGE_TILE

  const float sc = (QSCALE && col0 < kD) ? kQscale : 1.0f;
  float bv[4];
#pragma unroll
  for (int nt = 0; nt < 4; ++nt) bv[nt] = bias[col0 + wn + nt * 16 + l15];
#pragma unroll
  for (int mt = 0; mt < 4; ++mt)
#pragma unroll
    for (int i = 0; i < 4; ++i) {
      const size_t r = (size_t)(row0 + wm + mt * 16 + quad * 4 + i);
#pragma unroll
      for (int nt = 0; nt < 4; ++nt) {
        float v = (acc[mt][nt][i] + bv[nt]) * sc;
        const size_t cidx = r * (size_t)ldc + col0 + wn + nt * 16 + l15;
        if (OUT_BF16) ((unsigned short*)Cp)[cidx] = f2bf(v);
        else          ((float*)Cp)[cidx] = v;
      }
    }
}

// ---------------------------------------------------------------------------
// V transpose: qkvb V-slots [b*S+s][2048 + h*64 + d] -> vtb [(b*16+h)*64+d][s]
// ---------------------------------------------------------------------------
__global__ __launch_bounds__(256) void v_transpose(
    const unsigned short* __restrict__ qkvb, unsigned short* __restrict__ vtb) {
  __shared__ unsigned short L[64][72];  // +8 pad: 16B-aligned rows
  const int kt = blockIdx.x, h = blockIdx.y, b = blockIdx.z;
  const int t = threadIdx.x;
  const unsigned short* src = qkvb + (size_t)(b * kS) * k3D + 2 * kD + h * kDH;
#pragma unroll
  for (int p = 0; p < 2; ++p) {
    const int q = t + p * 256;
    const int r = q >> 3, c = q & 7;
    *(short8*)(&L[r][c * 8]) =
        *(const short8*)(src + (size_t)(kt * 64 + r) * k3D + c * 8);
  }
  __syncthreads();
  unsigned short* dst = vtb + (size_t)((b * kH + h) * kDH) * kS + kt * 64;
  const int key2 = (t & 31) * 2, dg = t >> 5;
#pragma unroll
  for (int i = 0; i < 8; ++i) {
    const int d = dg * 8 + i;
    ushort2 v = make_ushort2(L[key2][d], L[key2 + 1][d]);
    *(ushort2*)(dst + (size_t)d * kS + key2) = v;  // coalesced along keys
  }
}

// ---------------------------------------------------------------------------
// MFMA flash attention, S^T formulation, register-Q, pipelined staging,
// COMPLEMENTARY-PAIR BALANCED: block = (b, h, pair p) handles q-tiles p and
// 31-p (64 rows each). Causal work = (p+1) + (32-p) = 33 k-tiles for EVERY
// block -> zero tail, 4 blocks/CU (16 waves) sustained for the whole kernel.
// 24 KB LDS. 4 waves x 16 q-rows per q-tile.
// ---------------------------------------------------------------------------
__global__ __launch_bounds__(256, 4) void flash_attn_mfma(
    unsigned short* __restrict__ qkvb, const unsigned short* __restrict__ vtb,
    const int* __restrict__ cflag) {
  __shared__ unsigned short QP[4096];  // Q then P: [chunk 0..7][q 0..63][8] 8 KB
  __shared__ unsigned short Ks[4096];  // [dchunk 0..7][key 0..63][8]        8 KB
  __shared__ unsigned short Vt[4096];  // [keychunk 0..7][d 0..63][8]        8 KB

  const int pr = blockIdx.x;           // pair id 0..15
  const int h = blockIdx.y, b = blockIdx.z;
  const int t = threadIdx.x;
  const int lane = t & 63, l15 = lane & 15, quad = lane >> 4, w = t >> 6;
  const bool causal = (*cflag) != 0;

  unsigned short* qbase = qkvb + (size_t)(b * kS) * k3D + h * kDH;
  const unsigned short* vbase = vtb + (size_t)((b * kH + h) * kDH) * kS;
  const int c0 = t, c1 = t + 256;

  for (int half = 0; half < 2; ++half) {
    const int qt = half ? (31 - pr) : pr;
    const int q0 = qt * 64;
    const int ntiles = causal ? (qt + 1) : 32;

    // ---- prologue: stage Q (512 chunks) + K tile 0
    // (safe vs previous half: its last B_end ordered all LDS reads before this)
    async16(qbase + (size_t)(q0 + (c0 & 63)) * k3D + (c0 >> 6) * 8, QP + c0 * 8);
    async16(qbase + (size_t)(q0 + (c1 & 63)) * k3D + (c1 >> 6) * 8, QP + c1 * 8);
    async16(qbase + kD + (size_t)(c0 & 63) * k3D + (c0 >> 6) * 8, Ks + c0 * 8);
    async16(qbase + kD + (size_t)(c1 & 63) * k3D + (c1 >> 6) * 8, Ks + c1 * 8);
    __syncthreads();  // drains Q + K0

    // hoist Q fragments to registers — QP becomes the P buffer afterwards
    short8 bq[2];
#pragma unroll
    for (int kf = 0; kf < 2; ++kf)
      bq[kf] = *(const short8*)(
          QP + ((kf * 4 + quad) * 64 + w * 16 + l15) * 8);

    // V tile 0 (in flight across QK^T(0); drained at B_mid(0))
    async16(vbase + (size_t)(c0 & 63) * kS + (c0 >> 6) * 8, Vt + c0 * 8);
    async16(vbase + (size_t)(c1 & 63) * kS + (c1 >> 6) * 8, Vt + c1 * 8);

    f32x4 O[4] = {};                  // [d-tile ntd]; q row = w*16+quad*4+i
    float m_i = -3.0e38f, l_i = 0.f;  // per q (q = w*16+l15)

    for (int kt = 0; kt < ntiles; ++kt) {
      const int kk0 = kt * 64;

      // ---- S^T = K·Q^T: key = kk0+mt*16+quad*4+reg, q = w*16+l15
      f32x4 s[4];
#pragma unroll
      for (int mt = 0; mt < 4; ++mt) {
        short8 a0 = *(const short8*)(Ks + ((quad)*64 + mt * 16 + l15) * 8);
        short8 a1 = *(const short8*)(Ks + ((4 + quad) * 64 + mt * 16 + l15) * 8);
        f32x4 z = {};
        z = __builtin_amdgcn_mfma_f32_16x16x32_bf16(a0, bq[0], z, 0, 0, 0);
        z = __builtin_amdgcn_mfma_f32_16x16x32_bf16(a1, bq[1], z, 0, 0, 0);
        s[mt] = z;
      }

      __syncthreads();  // B_mid: drains V(kt); all QK^T reads of Ks complete

      // issue K(kt+1) — in flight across softmax + PV, drained at B_end
      if (kt + 1 < ntiles) {
        const int kn = kk0 + 64;
        async16(qbase + kD + (size_t)(kn + (c0 & 63)) * k3D + (c0 >> 6) * 8,
                Ks + c0 * 8);
        async16(qbase + kD + (size_t)(kn + (c1 & 63)) * k3D + (c1 >> 6) * 8,
                Ks + c1 * 8);
      }

      // ---- online softmax (scores in log2 domain; diagonal tile masked)
      const int gq = q0 + w * 16 + l15;
      if (causal && kt == ntiles - 1) {
#pragma unroll
        for (int mt = 0; mt < 4; ++mt)
#pragma unroll
          for (int i = 0; i < 4; ++i)
            if (kk0 + mt * 16 + quad * 4 + i > gq) s[mt][i] = -3.0e38f;
      }
      float mx = -3.0e38f;
#pragma unroll
      for (int mt = 0; mt < 4; ++mt)
#pragma unroll
        for (int i = 0; i < 4; ++i) mx = fmaxf(mx, s[mt][i]);
      mx = fmaxf(mx, __shfl_xor(mx, 16));
      mx = fmaxf(mx, __shfl_xor(mx, 32));
      const float mn = fmaxf(m_i, mx);
      const float alpha = exp2v(m_i - mn);
      m_i = mn;

      float p[4][4];
      float rs = 0.f;
#pragma unroll
      for (int mt = 0; mt < 4; ++mt)
#pragma unroll
        for (int i = 0; i < 4; ++i) {
          p[mt][i] = exp2v(s[mt][i] - mn);
          rs += p[mt][i];
        }
      rs += __shfl_xor(rs, 16);
      rs += __shfl_xor(rs, 32);
      l_i = l_i * alpha + rs;

      // packed P store: 4 consecutive keys (mt*16+quad*4 .. +3) at row gq
#pragma unroll
      for (int mt = 0; mt < 4; ++mt) {
        uint2 pk = make_uint2(pack2bf(p[mt][0], p[mt][1]),
                              pack2bf(p[mt][2], p[mt][3]));
        *(uint2*)(QP + ((mt * 2 + (quad >> 1)) * 64 + w * 16 + l15) * 8 +
                  (quad & 1) * 4) = pk;
      }

      // ---- rescale O by alpha of its own q-row (row = w*16 + quad*4 + i)
#pragma unroll
      for (int i = 0; i < 4; ++i) {
        const float a = __shfl(alpha, quad * 4 + i);
#pragma unroll
        for (int ntd = 0; ntd < 4; ++ntd) O[ntd][i] *= a;
      }

      // ---- O += P·V (P rows wave-private; Vt drained at B_mid)
#pragma unroll
      for (int kf = 0; kf < 2; ++kf) {
        short8 aP = *(const short8*)(
            QP + ((kf * 4 + quad) * 64 + w * 16 + l15) * 8);
#pragma unroll
        for (int ntd = 0; ntd < 4; ++ntd) {
          short8 bV = *(const short8*)(
              Vt + ((kf * 4 + quad) * 64 + ntd * 16 + l15) * 8);
          O[ntd] = __builtin_amdgcn_mfma_f32_16x16x32_bf16(
              aP, bV, O[ntd], 0, 0, 0);
        }
      }

      __syncthreads();  // B_end: drains K(kt+1); all PV reads of Vt/QP complete

      // issue V(kt+1) — in flight across next QK^T + softmax
      if (kt + 1 < ntiles) {
        const int kn = kk0 + 64;
        async16(vbase + (size_t)(c0 & 63) * kS + kn + (c0 >> 6) * 8, Vt + c0 * 8);
        async16(vbase + (size_t)(c1 & 63) * kS + kn + (c1 >> 6) * 8, Vt + c1 * 8);
      }
    }

    // ---- epilogue: /l, bf16, overwrite own Q slots
#pragma unroll
    for (int i = 0; i < 4; ++i) {
      const float linv = 1.0f / __shfl(l_i, quad * 4 + i);
      unsigned short* dst =
          qbase + (size_t)(q0 + w * 16 + quad * 4 + i) * k3D;
#pragma unroll
      for (int ntd = 0; ntd < 4; ++ntd)
        dst[ntd * 16 + l15] = f2bf(O[ntd][i] * linv);
    }
  }
}

// ---------------------------------------------------------------------------
extern "C" void kernel_launch(void* const* d_in, const int* in_sizes, int n_in,
                              void* d_out, int out_size, void* d_ws,
                              size_t ws_size, hipStream_t stream) {
  const float* x     = (const float*)d_in[0];
  const float* w_in  = (const float*)d_in[1];
  const float* b_in  = (const float*)d_in[2];
  const float* w_out = (const float*)d_in[3];
  const float* b_out = (const float*)d_in[4];
  const int*   cfl   = (const int*)d_in[5];
  float* out = (float*)d_out;

  // workspace layout (all 16B-aligned), total 92.3 MB
  char* ws = (char*)d_ws;
  unsigned short* qkvb = (unsigned short*)(ws);              // 8192x3072 bf16 = 48 MB
  unsigned short* xb   = (unsigned short*)(ws + 50331648);   // 8192x1024 bf16 = 16 MB
  unsigned short* wib  = (unsigned short*)(ws + 67108864);   // 3072x1024 bf16 =  6 MB
  unsigned short* wob  = (unsigned short*)(ws + 73400320);   // 1024x1024 bf16 =  2 MB
  unsigned short* vtb  = (unsigned short*)(ws + 75497472);   // [b,h,d,s] bf16 = 16 MB

  // 0) all three fp32->bf16 conversions in one launch
  cvt_bf16_3<<<(kM * kD + k3D * kD + kD * kD) / 4 / 256, 256, 0, stream>>>(
      x, w_in, w_out, xb, wib, wob);

  // 1) qkv = x @ w_in^T + b_in (bf16 out; Q cols pre-scaled by 0.125*log2e)
  gemm_mfma<true, true><<<dim3(k3D / 128, kM / 128), 256, 0, stream>>>(
      xb, kD, wib, kD, b_in, qkvb, k3D, kD);

  // 2) V transpose for PV staging
  v_transpose<<<dim3(kS / 64, kH, kB), 256, 0, stream>>>(qkvb, vtb);

  // 3) flash attention (pair-balanced, bf16 MFMA, register-Q, pipelined)
  flash_attn_mfma<<<dim3(16, kH, kB), 256, 0, stream>>>(qkvb, vtb, cfl);

  // 4) out = attn @ w_out^T + b_out (fp32 out; A rows inside qkvb, lda=3072)
  gemm_mfma<false, false><<<dim3(kD / 128, kM / 128), 256, 0, stream>>>(
      qkvb, k3D, wob, kD, b_out, out, kD, kD);
}

// Round 3
// 341.573 us; speedup vs baseline: 1.0572x; 1.0221x over previous
//
#include <hip/hip_runtime.h>
#include <hip/hip_bf16.h>
#include <stdint.h>

// Problem constants (B,S,D,H fixed by the reference)
constexpr int kB  = 4;
constexpr int kS  = 2048;
constexpr int kD  = 1024;
constexpr int kH  = 16;
constexpr int kDH = 64;
constexpr int kM  = kB * kS;     // 8192
constexpr int k3D = 3 * kD;      // 3072

// 0.125 (1/sqrt(DH)) * log2(e): scores leave GEMM1 in log2 domain -> exp2
constexpr float kQscale = 0.18033688011112042f;

typedef __attribute__((ext_vector_type(8))) short short8;  // 8 bf16 (4 VGPRs)
typedef __attribute__((ext_vector_type(4))) float f32x4;   // MFMA C/D

__device__ __forceinline__ float exp2v(float x) {
  return __builtin_amdgcn_exp2f(x);   // v_exp_f32 (base-2)
}

__device__ __forceinline__ unsigned short f2bf(float f) {
  unsigned u = __float_as_uint(f);
  u += 0x7fffu + ((u >> 16) & 1u);   // RNE
  return (unsigned short)(u >> 16);
}
__device__ __forceinline__ unsigned pack2bf(float a, float b) {
  return (unsigned)f2bf(a) | ((unsigned)f2bf(b) << 16);
}

// async global->LDS, 16B per lane. LDS dest must be wave-uniform base + lane*16.
__device__ __forceinline__ void async16(const void* g, void* l) {
  __builtin_amdgcn_global_load_lds(
      (const __attribute__((address_space(1))) unsigned int*)g,
      (__attribute__((address_space(3))) unsigned int*)l, 16, 0, 0);
}

// ---------------------------------------------------------------------------
// fp32 -> bf16 convert for all three inputs in one launch
// ---------------------------------------------------------------------------
__global__ __launch_bounds__(256) void cvt_bf16_3(
    const float* __restrict__ x, const float* __restrict__ wi,
    const float* __restrict__ wo, unsigned short* __restrict__ xb,
    unsigned short* __restrict__ wib, unsigned short* __restrict__ wob) {
  constexpr int n_x  = kM * kD / 4;
  constexpr int n_wi = k3D * kD / 4;
  int i = blockIdx.x * 256 + threadIdx.x;
  const float* src;
  unsigned short* dst;
  int j;
  if (i < n_x)            { src = x;  dst = xb;  j = i; }
  else if (i < n_x + n_wi){ src = wi; dst = wib; j = i - n_x; }
  else                    { src = wo; dst = wob; j = i - n_x - n_wi; }
  float4 v = ((const float4*)src)[j];
  ushort4 r;
  r.x = f2bf(v.x); r.y = f2bf(v.y); r.z = f2bf(v.z); r.w = f2bf(v.w);
  ((ushort4*)dst)[j] = r;
}

// ---------------------------------------------------------------------------
// 8-phase 256x256 MFMA GEMM (T2+T3+T4+T5 template, plain HIP).
// C[M][N] = A[M][K](bf16) @ Bt[N][K](bf16)^T + bias (fp32 acc).
// BM=BN=256, BK=64 (one full 128B cacheline per row per K-tile), 8 waves
// (2M x 4N, per-wave 128x64 output, acc[8][4]). LDS 128 KB: 2-slot double
// buffer, 32 KB per operand per slot. Per K-tile: 4 phases, snake quadrant
// order (0,0)->(1,0)->(1,1)->(0,1); each phase stages ONE half-tile of the
// NEXT K-tile (2 async16/thread), reads one frag-set, runs 16 MFMA between
// barrier pairs. Counted s_waitcnt vmcnt(2) once per K-tile - never 0 in
// the main loop (T4). setprio around MFMA (T5). LDS XOR-swizzle (T2,
// both-sides per rule 21): linear LDS dest, global source chunk
// pre-permuted c^(row&7), reads apply the same XOR -> stride-128B
// ds_read_b128 is 2-way (free) instead of 16-way conflicted.
// QSCALE: multiply (acc+bias) by kQscale for output cols < kD (Q columns;
// kD % 256 == 0 so the predicate is uniform per block).
// ---------------------------------------------------------------------------
template <bool OUT_BF16, bool QSCALE>
__global__ __launch_bounds__(512, 2) void gemm_mfma(
    const unsigned short* __restrict__ A, int lda,
    const unsigned short* __restrict__ Bt, int ldb,
    const float* __restrict__ bias, void* __restrict__ Cp, int ldc, int K) {
  __shared__ unsigned short Asl[2][16384];  // 2 x 32 KB
  __shared__ unsigned short Bsl[2][16384];  // 2 x 32 KB
  const int t = threadIdx.x;
  const int lane = t & 63, l15 = lane & 15, quad = lane >> 4, w = t >> 6;

  // Bijective XCD swizzle (both grids have nwg % 8 == 0; guarded anyway)
  const int nwg = gridDim.x * gridDim.y;
  int bid = blockIdx.y * gridDim.x + blockIdx.x;
  if ((nwg & 7) == 0) bid = (bid & 7) * (nwg >> 3) + (bid >> 3);
  const int bx = bid % gridDim.x, by = bid / gridDim.x;
  const int row0 = by * 256, col0 = bx * 256;
  const int wm = (w & 1) * 128, wn = (w >> 1) * 64;

  f32x4 acc[8][4] = {};  // [mq*4+mt][nq*2+nt]

  // Staging: thread q covers LDS slots {q, q+512} of each 1024-slot half-tile
  // (half-tile = 128 rows x 128 B). slot s -> r_local = s>>3, c_lin = s&7.
  // Logical chunk stored at c_lin is c = c_lin ^ (r_local&7)  (involution).
  // Global source for (h, s): row = row0/col0 + h*128 + r_local, elem c*8.
  const unsigned short* gA[2][2];
  const unsigned short* gB[2][2];
#pragma unroll
  for (int h = 0; h < 2; ++h)
#pragma unroll
    for (int ss = 0; ss < 2; ++ss) {
      const int s = t + ss * 512;
      const int r = s >> 3, c = (s & 7) ^ (r & 7);
      gA[h][ss] = A  + (size_t)(row0 + h * 128 + r) * lda + c * 8;
      gB[h][ss] = Bt + (size_t)(col0 + h * 128 + r) * ldb + c * 8;
    }

  // LDS dest is LINEAR in s (wave-uniform base + lane*16) -> gload_lds legal.
#define STG_A(h, buf, k0)                                              \
  do {                                                                 \
    async16(gA[h][0] + (k0), Asl[buf] + (h) * 8192 + t * 8);           \
    async16(gA[h][1] + (k0), Asl[buf] + (h) * 8192 + (t + 512) * 8);   \
  } while (0)
#define STG_B(h, buf, k0)                                              \
  do {                                                                 \
    async16(gB[h][0] + (k0), Bsl[buf] + (h) * 8192 + t * 8);           \
    async16(gB[h][1] + (k0), Bsl[buf] + (h) * 8192 + (t + 512) * 8);   \
  } while (0)

  // Swizzled frag reads: row*64 shorts per row (128 B), chunk XOR (row&7).
  // row & 7 == l15 & 7 (wm, mq*64, mt*16, nq*32, nt*16 all multiples of 8).
#define ARD(mq, mt, ks)                                                  \
  (*(const short8*)(as + (wm + (mq) * 64 + (mt) * 16 + l15) * 64 +       \
                    ((((ks) * 4 + quad) ^ (l15 & 7)) * 8)))
#define BRD(nq, nt, ks)                                                  \
  (*(const short8*)(bs + (wn + (nq) * 32 + (nt) * 16 + l15) * 64 +       \
                    ((((ks) * 4 + quad) ^ (l15 & 7)) * 8)))

  const int nkt = K / 64;  // 16 here
  // prologue: K-tile 0 into slot 0 (8 loads in flight)
  STG_A(0, 0, 0); STG_A(1, 0, 0); STG_B(0, 0, 0); STG_B(1, 0, 0);

  short8 af[2][4][2];  // [mq][mt][ks] — both m-halves held across the K-tile
  short8 bf[2][2];     // [nt][ks]    — current n-half only

  for (int kt = 0; kt < nkt; ++kt) {
    const int buf = kt & 1, nbuf = buf ^ 1;
    const int k0n = (kt + 1) * 64;
    const bool pf = (kt + 1 < nkt);
    const unsigned short* as = Asl[buf];
    const unsigned short* bs = Bsl[buf];

    // ---- P1: quadrant (0,0); stage next A-half0; counted vmcnt ----------
    if (pf) {
      STG_A(0, nbuf, k0n);
      asm volatile("s_waitcnt vmcnt(2)" ::: "memory");  // kt fully landed
    } else {
      asm volatile("s_waitcnt vmcnt(0)" ::: "memory");  // final drain
    }
    __builtin_amdgcn_s_barrier();
    __builtin_amdgcn_sched_barrier(0);
#pragma unroll
    for (int mt = 0; mt < 4; ++mt)
#pragma unroll
      for (int ks = 0; ks < 2; ++ks) af[0][mt][ks] = ARD(0, mt, ks);
#pragma unroll
    for (int nt = 0; nt < 2; ++nt)
#pragma unroll
      for (int ks = 0; ks < 2; ++ks) bf[nt][ks] = BRD(0, nt, ks);
    __builtin_amdgcn_s_setprio(1);
#pragma unroll
    for (int mt = 0; mt < 4; ++mt)
#pragma unroll
      for (int nt = 0; nt < 2; ++nt)
#pragma unroll
        for (int ks = 0; ks < 2; ++ks)
          acc[mt][nt] = __builtin_amdgcn_mfma_f32_16x16x32_bf16(
              af[0][mt][ks], bf[nt][ks], acc[mt][nt], 0, 0, 0);
    __builtin_amdgcn_s_setprio(0);
    __builtin_amdgcn_sched_barrier(0);
    __builtin_amdgcn_s_barrier();

    // ---- P2: quadrant (1,0); stage next A-half1 --------------------------
    if (pf) STG_A(1, nbuf, k0n);
    __builtin_amdgcn_s_barrier();
    __builtin_amdgcn_sched_barrier(0);
#pragma unroll
    for (int mt = 0; mt < 4; ++mt)
#pragma unroll
      for (int ks = 0; ks < 2; ++ks) af[1][mt][ks] = ARD(1, mt, ks);
    __builtin_amdgcn_s_setprio(1);
#pragma unroll
    for (int mt = 0; mt < 4; ++mt)
#pragma unroll
      for (int nt = 0; nt < 2; ++nt)
#pragma unroll
        for (int ks = 0; ks < 2; ++ks)
          acc[4 + mt][nt] = __builtin_amdgcn_mfma_f32_16x16x32_bf16(
              af[1][mt][ks], bf[nt][ks], acc[4 + mt][nt], 0, 0, 0);
    __builtin_amdgcn_s_setprio(0);
    __builtin_amdgcn_sched_barrier(0);
    __builtin_amdgcn_s_barrier();

    // ---- P3: quadrant (1,1); stage next B-half0 --------------------------
    if (pf) STG_B(0, nbuf, k0n);
    __builtin_amdgcn_s_barrier();
    __builtin_amdgcn_sched_barrier(0);
#pragma unroll
    for (int nt = 0; nt < 2; ++nt)
#pragma unroll
      for (int ks = 0; ks < 2; ++ks) bf[nt][ks] = BRD(1, nt, ks);
    __builtin_amdgcn_s_setprio(1);
#pragma unroll
    for (int mt = 0; mt < 4; ++mt)
#pragma unroll
      for (int nt = 0; nt < 2; ++nt)
#pragma unroll
        for (int ks = 0; ks < 2; ++ks)
          acc[4 + mt][2 + nt] = __builtin_amdgcn_mfma_f32_16x16x32_bf16(
              af[1][mt][ks], bf[nt][ks], acc[4 + mt][2 + nt], 0, 0, 0);
    __builtin_amdgcn_s_setprio(0);
    __builtin_amdgcn_sched_barrier(0);
    __builtin_amdgcn_s_barrier();

    // ---- P4: quadrant (0,1); stage next B-half1 (af0/bf1 held, no reads) -
    if (pf) STG_B(1, nbuf, k0n);
    __builtin_amdgcn_s_barrier();
    __builtin_amdgcn_sched_barrier(0);
    __builtin_amdgcn_s_setprio(1);
#pragma unroll
    for (int mt = 0; mt < 4; ++mt)
#pragma unroll
      for (int nt = 0; nt < 2; ++nt)
#pragma unroll
        for (int ks = 0; ks < 2; ++ks)
          acc[mt][2 + nt] = __builtin_amdgcn_mfma_f32_16x16x32_bf16(
              af[0][mt][ks], bf[nt][ks], acc[mt][2 + nt], 0, 0, 0);
    __builtin_amdgcn_s_setprio(0);
    __builtin_amdgcn_sched_barrier(0);
    __builtin_amdgcn_s_barrier();
  }
#undef STG_A
#undef STG_B
#undef ARD
#undef BRD

  const float sc = (QSCALE && col0 < kD) ? kQscale : 1.0f;
  float bv[4];
#pragma unroll
  for (int n = 0; n < 4; ++n)
    bv[n] = bias[col0 + wn + (n >> 1) * 32 + (n & 1) * 16 + l15];
#pragma unroll
  for (int m = 0; m < 8; ++m)
#pragma unroll
    for (int i = 0; i < 4; ++i) {
      const size_t r =
          (size_t)(row0 + wm + (m >> 2) * 64 + (m & 3) * 16 + quad * 4 + i);
#pragma unroll
      for (int n = 0; n < 4; ++n) {
        float v = (acc[m][n][i] + bv[n]) * sc;
        const size_t cidx =
            r * (size_t)ldc + col0 + wn + (n >> 1) * 32 + (n & 1) * 16 + l15;
        if (OUT_BF16) ((unsigned short*)Cp)[cidx] = f2bf(v);
        else          ((float*)Cp)[cidx] = v;
      }
    }
}

// ---------------------------------------------------------------------------
// V transpose: qkvb V-slots [b*S+s][2048 + h*64 + d] -> vtb [(b*16+h)*64+d][s]
// ---------------------------------------------------------------------------
__global__ __launch_bounds__(256) void v_transpose(
    const unsigned short* __restrict__ qkvb, unsigned short* __restrict__ vtb) {
  __shared__ unsigned short L[64][72];  // +8 pad: 16B-aligned rows
  const int kt = blockIdx.x, h = blockIdx.y, b = blockIdx.z;
  const int t = threadIdx.x;
  const unsigned short* src = qkvb + (size_t)(b * kS) * k3D + 2 * kD + h * kDH;
#pragma unroll
  for (int p = 0; p < 2; ++p) {
    const int q = t + p * 256;
    const int r = q >> 3, c = q & 7;
    *(short8*)(&L[r][c * 8]) =
        *(const short8*)(src + (size_t)(kt * 64 + r) * k3D + c * 8);
  }
  __syncthreads();
  unsigned short* dst = vtb + (size_t)((b * kH + h) * kDH) * kS + kt * 64;
  const int key2 = (t & 31) * 2, dg = t >> 5;
#pragma unroll
  for (int i = 0; i < 8; ++i) {
    const int d = dg * 8 + i;
    ushort2 v = make_ushort2(L[key2][d], L[key2 + 1][d]);
    *(ushort2*)(dst + (size_t)d * kS + key2) = v;  // coalesced along keys
  }
}

// ---------------------------------------------------------------------------
// MFMA flash attention, S^T formulation, register-Q, pipelined staging,
// COMPLEMENTARY-PAIR BALANCED: block = (b, h, pair p) handles q-tiles p and
// 31-p (64 rows each). Causal work = (p+1) + (32-p) = 33 k-tiles for EVERY
// block -> zero tail, 4 blocks/CU (16 waves) sustained for the whole kernel.
// 24 KB LDS. 4 waves x 16 q-rows per q-tile.
// ---------------------------------------------------------------------------
__global__ __launch_bounds__(256, 4) void flash_attn_mfma(
    unsigned short* __restrict__ qkvb, const unsigned short* __restrict__ vtb,
    const int* __restrict__ cflag) {
  __shared__ unsigned short QP[4096];  // Q then P: [chunk 0..7][q 0..63][8] 8 KB
  __shared__ unsigned short Ks[4096];  // [dchunk 0..7][key 0..63][8]        8 KB
  __shared__ unsigned short Vt[4096];  // [keychunk 0..7][d 0..63][8]        8 KB

  const int pr = blockIdx.x;           // pair id 0..15
  const int h = blockIdx.y, b = blockIdx.z;
  const int t = threadIdx.x;
  const int lane = t & 63, l15 = lane & 15, quad = lane >> 4, w = t >> 6;
  const bool causal = (*cflag) != 0;

  unsigned short* qbase = qkvb + (size_t)(b * kS) * k3D + h * kDH;
  const unsigned short* vbase = vtb + (size_t)((b * kH + h) * kDH) * kS;
  const int c0 = t, c1 = t + 256;

  for (int half = 0; half < 2; ++half) {
    const int qt = half ? (31 - pr) : pr;
    const int q0 = qt * 64;
    const int ntiles = causal ? (qt + 1) : 32;

    // ---- prologue: stage Q (512 chunks) + K tile 0
    // (safe vs previous half: its last B_end ordered all LDS reads before this)
    async16(qbase + (size_t)(q0 + (c0 & 63)) * k3D + (c0 >> 6) * 8, QP + c0 * 8);
    async16(qbase + (size_t)(q0 + (c1 & 63)) * k3D + (c1 >> 6) * 8, QP + c1 * 8);
    async16(qbase + kD + (size_t)(c0 & 63) * k3D + (c0 >> 6) * 8, Ks + c0 * 8);
    async16(qbase + kD + (size_t)(c1 & 63) * k3D + (c1 >> 6) * 8, Ks + c1 * 8);
    __syncthreads();  // drains Q + K0

    // hoist Q fragments to registers — QP becomes the P buffer afterwards
    short8 bq[2];
#pragma unroll
    for (int kf = 0; kf < 2; ++kf)
      bq[kf] = *(const short8*)(
          QP + ((kf * 4 + quad) * 64 + w * 16 + l15) * 8);

    // V tile 0 (in flight across QK^T(0); drained at B_mid(0))
    async16(vbase + (size_t)(c0 & 63) * kS + (c0 >> 6) * 8, Vt + c0 * 8);
    async16(vbase + (size_t)(c1 & 63) * kS + (c1 >> 6) * 8, Vt + c1 * 8);

    f32x4 O[4] = {};                  // [d-tile ntd]; q row = w*16+quad*4+i
    float m_i = -3.0e38f, l_i = 0.f;  // per q (q = w*16+l15)

    for (int kt = 0; kt < ntiles; ++kt) {
      const int kk0 = kt * 64;

      // ---- S^T = K·Q^T: key = kk0+mt*16+quad*4+reg, q = w*16+l15
      f32x4 s[4];
#pragma unroll
      for (int mt = 0; mt < 4; ++mt) {
        short8 a0 = *(const short8*)(Ks + ((quad)*64 + mt * 16 + l15) * 8);
        short8 a1 = *(const short8*)(Ks + ((4 + quad) * 64 + mt * 16 + l15) * 8);
        f32x4 z = {};
        z = __builtin_amdgcn_mfma_f32_16x16x32_bf16(a0, bq[0], z, 0, 0, 0);
        z = __builtin_amdgcn_mfma_f32_16x16x32_bf16(a1, bq[1], z, 0, 0, 0);
        s[mt] = z;
      }

      __syncthreads();  // B_mid: drains V(kt); all QK^T reads of Ks complete

      // issue K(kt+1) — in flight across softmax + PV, drained at B_end
      if (kt + 1 < ntiles) {
        const int kn = kk0 + 64;
        async16(qbase + kD + (size_t)(kn + (c0 & 63)) * k3D + (c0 >> 6) * 8,
                Ks + c0 * 8);
        async16(qbase + kD + (size_t)(kn + (c1 & 63)) * k3D + (c1 >> 6) * 8,
                Ks + c1 * 8);
      }

      // ---- online softmax (scores in log2 domain; diagonal tile masked)
      const int gq = q0 + w * 16 + l15;
      if (causal && kt == ntiles - 1) {
#pragma unroll
        for (int mt = 0; mt < 4; ++mt)
#pragma unroll
          for (int i = 0; i < 4; ++i)
            if (kk0 + mt * 16 + quad * 4 + i > gq) s[mt][i] = -3.0e38f;
      }
      float mx = -3.0e38f;
#pragma unroll
      for (int mt = 0; mt < 4; ++mt)
#pragma unroll
        for (int i = 0; i < 4; ++i) mx = fmaxf(mx, s[mt][i]);
      mx = fmaxf(mx, __shfl_xor(mx, 16));
      mx = fmaxf(mx, __shfl_xor(mx, 32));
      const float mn = fmaxf(m_i, mx);
      const float alpha = exp2v(m_i - mn);
      m_i = mn;

      float p[4][4];
      float rs = 0.f;
#pragma unroll
      for (int mt = 0; mt < 4; ++mt)
#pragma unroll
        for (int i = 0; i < 4; ++i) {
          p[mt][i] = exp2v(s[mt][i] - mn);
          rs += p[mt][i];
        }
      rs += __shfl_xor(rs, 16);
      rs += __shfl_xor(rs, 32);
      l_i = l_i * alpha + rs;

      // packed P store: 4 consecutive keys (mt*16+quad*4 .. +3) at row gq
#pragma unroll
      for (int mt = 0; mt < 4; ++mt) {
        uint2 pk = make_uint2(pack2bf(p[mt][0], p[mt][1]),
                              pack2bf(p[mt][2], p[mt][3]));
        *(uint2*)(QP + ((mt * 2 + (quad >> 1)) * 64 + w * 16 + l15) * 8 +
                  (quad & 1) * 4) = pk;
      }

      // ---- rescale O by alpha of its own q-row (row = w*16 + quad*4 + i)
#pragma unroll
      for (int i = 0; i < 4; ++i) {
        const float a = __shfl(alpha, quad * 4 + i);
#pragma unroll
        for (int ntd = 0; ntd < 4; ++ntd) O[ntd][i] *= a;
      }

      // ---- O += P·V (P rows wave-private; Vt drained at B_mid)
#pragma unroll
      for (int kf = 0; kf < 2; ++kf) {
        short8 aP = *(const short8*)(
            QP + ((kf * 4 + quad) * 64 + w * 16 + l15) * 8);
#pragma unroll
        for (int ntd = 0; ntd < 4; ++ntd) {
          short8 bV = *(const short8*)(
              Vt + ((kf * 4 + quad) * 64 + ntd * 16 + l15) * 8);
          O[ntd] = __builtin_amdgcn_mfma_f32_16x16x32_bf16(
              aP, bV, O[ntd], 0, 0, 0);
        }
      }

      __syncthreads();  // B_end: drains K(kt+1); all PV reads of Vt/QP complete

      // issue V(kt+1) — in flight across next QK^T + softmax
      if (kt + 1 < ntiles) {
        const int kn = kk0 + 64;
        async16(vbase + (size_t)(c0 & 63) * kS + kn + (c0 >> 6) * 8, Vt + c0 * 8);
        async16(vbase + (size_t)(c1 & 63) * kS + kn + (c1 >> 6) * 8, Vt + c1 * 8);
      }
    }

    // ---- epilogue: /l, bf16, overwrite own Q slots
#pragma unroll
    for (int i = 0; i < 4; ++i) {
      const float linv = 1.0f / __shfl(l_i, quad * 4 + i);
      unsigned short* dst =
          qbase + (size_t)(q0 + w * 16 + quad * 4 + i) * k3D;
#pragma unroll
      for (int ntd = 0; ntd < 4; ++ntd)
        dst[ntd * 16 + l15] = f2bf(O[ntd][i] * linv);
    }
  }
}

// ---------------------------------------------------------------------------
extern "C" void kernel_launch(void* const* d_in, const int* in_sizes, int n_in,
                              void* d_out, int out_size, void* d_ws,
                              size_t ws_size, hipStream_t stream) {
  const float* x     = (const float*)d_in[0];
  const float* w_in  = (const float*)d_in[1];
  const float* b_in  = (const float*)d_in[2];
  const float* w_out = (const float*)d_in[3];
  const float* b_out = (const float*)d_in[4];
  const int*   cfl   = (const int*)d_in[5];
  float* out = (float*)d_out;

  // workspace layout (all 16B-aligned), total 92.3 MB
  char* ws = (char*)d_ws;
  unsigned short* qkvb = (unsigned short*)(ws);              // 8192x3072 bf16 = 48 MB
  unsigned short* xb   = (unsigned short*)(ws + 50331648);   // 8192x1024 bf16 = 16 MB
  unsigned short* wib  = (unsigned short*)(ws + 67108864);   // 3072x1024 bf16 =  6 MB
  unsigned short* wob  = (unsigned short*)(ws + 73400320);   // 1024x1024 bf16 =  2 MB
  unsigned short* vtb  = (unsigned short*)(ws + 75497472);   // [b,h,d,s] bf16 = 16 MB

  // 0) all three fp32->bf16 conversions in one launch
  cvt_bf16_3<<<(kM * kD + k3D * kD + kD * kD) / 4 / 256, 256, 0, stream>>>(
      x, w_in, w_out, xb, wib, wob);

  // 1) qkv = x @ w_in^T + b_in (bf16 out; Q cols pre-scaled by 0.125*log2e)
  //    256x256 tile, 512 threads: grid 12x32 = 384 blocks
  gemm_mfma<true, true><<<dim3(k3D / 256, kM / 256), 512, 0, stream>>>(
      xb, kD, wib, kD, b_in, qkvb, k3D, kD);

  // 2) V transpose for PV staging
  v_transpose<<<dim3(kS / 64, kH, kB), 256, 0, stream>>>(qkvb, vtb);

  // 3) flash attention (pair-balanced, bf16 MFMA, register-Q, pipelined)
  flash_attn_mfma<<<dim3(16, kH, kB), 256, 0, stream>>>(qkvb, vtb, cfl);

  // 4) out = attn @ w_out^T + b_out (fp32 out; A rows inside qkvb, lda=3072)
  //    256x256 tile: grid 4x32 = 128 blocks
  gemm_mfma<false, false><<<dim3(kD / 256, kM / 256), 512, 0, stream>>>(
      qkvb, k3D, wob, kD, b_out, out, kD, kD);
}

// Round 4
// 315.612 us; speedup vs baseline: 1.1442x; 1.0823x over previous
//
#include <hip/hip_runtime.h>
#include <hip/hip_bf16.h>
#include <stdint.h>

// Problem constants (B,S,D,H fixed by the reference)
constexpr int kB  = 4;
constexpr int kS  = 2048;
constexpr int kD  = 1024;
constexpr int kH  = 16;
constexpr int kDH = 64;
constexpr int kM  = kB * kS;     // 8192
constexpr int k3D = 3 * kD;      // 3072

// 0.125 (1/sqrt(DH)) * log2(e): scores leave GEMM1 in log2 domain -> exp2
constexpr float kQscale = 0.18033688011112042f;

typedef __attribute__((ext_vector_type(8))) short short8;  // 8 bf16 (4 VGPRs)
typedef __attribute__((ext_vector_type(4))) float f32x4;   // MFMA C/D

__device__ __forceinline__ float exp2v(float x) {
  return __builtin_amdgcn_exp2f(x);   // v_exp_f32 (base-2)
}

__device__ __forceinline__ unsigned short f2bf(float f) {
  unsigned u = __float_as_uint(f);
  u += 0x7fffu + ((u >> 16) & 1u);   // RNE
  return (unsigned short)(u >> 16);
}

// packed f32x2 -> bf16x2 (low = lo), single HW instr (T12 primitive)
__device__ __forceinline__ unsigned cvtpk2bf(float lo, float hi) {
  unsigned r;
  asm("v_cvt_pk_bf16_f32 %0, %1, %2" : "=v"(r) : "v"(lo), "v"(hi));
  return r;
}

// async global->LDS, 16B per lane. LDS dest must be wave-uniform base + lane*16.
__device__ __forceinline__ void async16(const void* g, void* l) {
  __builtin_amdgcn_global_load_lds(
      (const __attribute__((address_space(1))) unsigned int*)g,
      (__attribute__((address_space(3))) unsigned int*)l, 16, 0, 0);
}

// ---------------------------------------------------------------------------
// fp32 -> bf16 convert for all three inputs in one launch
// ---------------------------------------------------------------------------
__global__ __launch_bounds__(256) void cvt_bf16_3(
    const float* __restrict__ x, const float* __restrict__ wi,
    const float* __restrict__ wo, unsigned short* __restrict__ xb,
    unsigned short* __restrict__ wib, unsigned short* __restrict__ wob) {
  constexpr int n_x  = kM * kD / 4;
  constexpr int n_wi = k3D * kD / 4;
  int i = blockIdx.x * 256 + threadIdx.x;
  const float* src;
  unsigned short* dst;
  int j;
  if (i < n_x)            { src = x;  dst = xb;  j = i; }
  else if (i < n_x + n_wi){ src = wi; dst = wib; j = i - n_x; }
  else                    { src = wo; dst = wob; j = i - n_x - n_wi; }
  float4 v = ((const float4*)src)[j];
  ushort4 r;
  r.x = f2bf(v.x); r.y = f2bf(v.y); r.z = f2bf(v.z); r.w = f2bf(v.w);
  ((ushort4*)dst)[j] = r;
}

// ---------------------------------------------------------------------------
// 8-phase 256x256 MFMA GEMM (T2+T3+T4+T5 template, plain HIP). Unchanged
// from round 3 (verified passing).
// ---------------------------------------------------------------------------
template <bool OUT_BF16, bool QSCALE>
__global__ __launch_bounds__(512, 2) void gemm_mfma(
    const unsigned short* __restrict__ A, int lda,
    const unsigned short* __restrict__ Bt, int ldb,
    const float* __restrict__ bias, void* __restrict__ Cp, int ldc, int K) {
  __shared__ unsigned short Asl[2][16384];  // 2 x 32 KB
  __shared__ unsigned short Bsl[2][16384];  // 2 x 32 KB
  const int t = threadIdx.x;
  const int lane = t & 63, l15 = lane & 15, quad = lane >> 4, w = t >> 6;

  // Bijective XCD swizzle (both grids have nwg % 8 == 0; guarded anyway)
  const int nwg = gridDim.x * gridDim.y;
  int bid = blockIdx.y * gridDim.x + blockIdx.x;
  if ((nwg & 7) == 0) bid = (bid & 7) * (nwg >> 3) + (bid >> 3);
  const int bx = bid % gridDim.x, by = bid / gridDim.x;
  const int row0 = by * 256, col0 = bx * 256;
  const int wm = (w & 1) * 128, wn = (w >> 1) * 64;

  f32x4 acc[8][4] = {};  // [mq*4+mt][nq*2+nt]

  const unsigned short* gA[2][2];
  const unsigned short* gB[2][2];
#pragma unroll
  for (int h = 0; h < 2; ++h)
#pragma unroll
    for (int ss = 0; ss < 2; ++ss) {
      const int s = t + ss * 512;
      const int r = s >> 3, c = (s & 7) ^ (r & 7);
      gA[h][ss] = A  + (size_t)(row0 + h * 128 + r) * lda + c * 8;
      gB[h][ss] = Bt + (size_t)(col0 + h * 128 + r) * ldb + c * 8;
    }

#define STG_A(h, buf, k0)                                              \
  do {                                                                 \
    async16(gA[h][0] + (k0), Asl[buf] + (h) * 8192 + t * 8);           \
    async16(gA[h][1] + (k0), Asl[buf] + (h) * 8192 + (t + 512) * 8);   \
  } while (0)
#define STG_B(h, buf, k0)                                              \
  do {                                                                 \
    async16(gB[h][0] + (k0), Bsl[buf] + (h) * 8192 + t * 8);           \
    async16(gB[h][1] + (k0), Bsl[buf] + (h) * 8192 + (t + 512) * 8);   \
  } while (0)

#define ARD(mq, mt, ks)                                                  \
  (*(const short8*)(as + (wm + (mq) * 64 + (mt) * 16 + l15) * 64 +       \
                    ((((ks) * 4 + quad) ^ (l15 & 7)) * 8)))
#define BRD(nq, nt, ks)                                                  \
  (*(const short8*)(bs + (wn + (nq) * 32 + (nt) * 16 + l15) * 64 +       \
                    ((((ks) * 4 + quad) ^ (l15 & 7)) * 8)))

  const int nkt = K / 64;  // 16 here
  STG_A(0, 0, 0); STG_A(1, 0, 0); STG_B(0, 0, 0); STG_B(1, 0, 0);

  short8 af[2][4][2];
  short8 bf[2][2];

  for (int kt = 0; kt < nkt; ++kt) {
    const int buf = kt & 1, nbuf = buf ^ 1;
    const int k0n = (kt + 1) * 64;
    const bool pf = (kt + 1 < nkt);
    const unsigned short* as = Asl[buf];
    const unsigned short* bs = Bsl[buf];

    // ---- P1: quadrant (0,0); stage next A-half0; counted vmcnt ----------
    if (pf) {
      STG_A(0, nbuf, k0n);
      asm volatile("s_waitcnt vmcnt(2)" ::: "memory");
    } else {
      asm volatile("s_waitcnt vmcnt(0)" ::: "memory");
    }
    __builtin_amdgcn_s_barrier();
    __builtin_amdgcn_sched_barrier(0);
#pragma unroll
    for (int mt = 0; mt < 4; ++mt)
#pragma unroll
      for (int ks = 0; ks < 2; ++ks) af[0][mt][ks] = ARD(0, mt, ks);
#pragma unroll
    for (int nt = 0; nt < 2; ++nt)
#pragma unroll
      for (int ks = 0; ks < 2; ++ks) bf[nt][ks] = BRD(0, nt, ks);
    __builtin_amdgcn_s_setprio(1);
#pragma unroll
    for (int mt = 0; mt < 4; ++mt)
#pragma unroll
      for (int nt = 0; nt < 2; ++nt)
#pragma unroll
        for (int ks = 0; ks < 2; ++ks)
          acc[mt][nt] = __builtin_amdgcn_mfma_f32_16x16x32_bf16(
              af[0][mt][ks], bf[nt][ks], acc[mt][nt], 0, 0, 0);
    __builtin_amdgcn_s_setprio(0);
    __builtin_amdgcn_sched_barrier(0);
    __builtin_amdgcn_s_barrier();

    // ---- P2: quadrant (1,0); stage next A-half1 --------------------------
    if (pf) STG_A(1, nbuf, k0n);
    __builtin_amdgcn_s_barrier();
    __builtin_amdgcn_sched_barrier(0);
#pragma unroll
    for (int mt = 0; mt < 4; ++mt)
#pragma unroll
      for (int ks = 0; ks < 2; ++ks) af[1][mt][ks] = ARD(1, mt, ks);
    __builtin_amdgcn_s_setprio(1);
#pragma unroll
    for (int mt = 0; mt < 4; ++mt)
#pragma unroll
      for (int nt = 0; nt < 2; ++nt)
#pragma unroll
        for (int ks = 0; ks < 2; ++ks)
          acc[4 + mt][nt] = __builtin_amdgcn_mfma_f32_16x16x32_bf16(
              af[1][mt][ks], bf[nt][ks], acc[4 + mt][nt], 0, 0, 0);
    __builtin_amdgcn_s_setprio(0);
    __builtin_amdgcn_sched_barrier(0);
    __builtin_amdgcn_s_barrier();

    // ---- P3: quadrant (1,1); stage next B-half0 --------------------------
    if (pf) STG_B(0, nbuf, k0n);
    __builtin_amdgcn_s_barrier();
    __builtin_amdgcn_sched_barrier(0);
#pragma unroll
    for (int nt = 0; nt < 2; ++nt)
#pragma unroll
      for (int ks = 0; ks < 2; ++ks) bf[nt][ks] = BRD(1, nt, ks);
    __builtin_amdgcn_s_setprio(1);
#pragma unroll
    for (int mt = 0; mt < 4; ++mt)
#pragma unroll
      for (int nt = 0; nt < 2; ++nt)
#pragma unroll
        for (int ks = 0; ks < 2; ++ks)
          acc[4 + mt][2 + nt] = __builtin_amdgcn_mfma_f32_16x16x32_bf16(
              af[1][mt][ks], bf[nt][ks], acc[4 + mt][2 + nt], 0, 0, 0);
    __builtin_amdgcn_s_setprio(0);
    __builtin_amdgcn_sched_barrier(0);
    __builtin_amdgcn_s_barrier();

    // ---- P4: quadrant (0,1); stage next B-half1 (af0/bf1 held, no reads) -
    if (pf) STG_B(1, nbuf, k0n);
    __builtin_amdgcn_s_barrier();
    __builtin_amdgcn_sched_barrier(0);
    __builtin_amdgcn_s_setprio(1);
#pragma unroll
    for (int mt = 0; mt < 4; ++mt)
#pragma unroll
      for (int nt = 0; nt < 2; ++nt)
#pragma unroll
        for (int ks = 0; ks < 2; ++ks)
          acc[mt][2 + nt] = __builtin_amdgcn_mfma_f32_16x16x32_bf16(
              af[0][mt][ks], bf[nt][ks], acc[mt][2 + nt], 0, 0, 0);
    __builtin_amdgcn_s_setprio(0);
    __builtin_amdgcn_sched_barrier(0);
    __builtin_amdgcn_s_barrier();
  }
#undef STG_A
#undef STG_B
#undef ARD
#undef BRD

  const float sc = (QSCALE && col0 < kD) ? kQscale : 1.0f;
  float bv[4];
#pragma unroll
  for (int n = 0; n < 4; ++n)
    bv[n] = bias[col0 + wn + (n >> 1) * 32 + (n & 1) * 16 + l15];
#pragma unroll
  for (int m = 0; m < 8; ++m)
#pragma unroll
    for (int i = 0; i < 4; ++i) {
      const size_t r =
          (size_t)(row0 + wm + (m >> 2) * 64 + (m & 3) * 16 + quad * 4 + i);
#pragma unroll
      for (int n = 0; n < 4; ++n) {
        float v = (acc[m][n][i] + bv[n]) * sc;
        const size_t cidx =
            r * (size_t)ldc + col0 + wn + (n >> 1) * 32 + (n & 1) * 16 + l15;
        if (OUT_BF16) ((unsigned short*)Cp)[cidx] = f2bf(v);
        else          ((float*)Cp)[cidx] = v;
      }
    }
}

// ---------------------------------------------------------------------------
// V transpose: qkvb V-slots [b*S+s][2048 + h*64 + d] -> vtb [(b*16+h)*64+d][s]
// ---------------------------------------------------------------------------
__global__ __launch_bounds__(256) void v_transpose(
    const unsigned short* __restrict__ qkvb, unsigned short* __restrict__ vtb) {
  __shared__ unsigned short L[64][72];  // +8 pad: 16B-aligned rows
  const int kt = blockIdx.x, h = blockIdx.y, b = blockIdx.z;
  const int t = threadIdx.x;
  const unsigned short* src = qkvb + (size_t)(b * kS) * k3D + 2 * kD + h * kDH;
#pragma unroll
  for (int p = 0; p < 2; ++p) {
    const int q = t + p * 256;
    const int r = q >> 3, c = q & 7;
    *(short8*)(&L[r][c * 8]) =
        *(const short8*)(src + (size_t)(kt * 64 + r) * k3D + c * 8);
  }
  __syncthreads();
  unsigned short* dst = vtb + (size_t)((b * kH + h) * kDH) * kS + kt * 64;
  const int key2 = (t & 31) * 2, dg = t >> 5;
#pragma unroll
  for (int i = 0; i < 8; ++i) {
    const int d = dg * 8 + i;
    ushort2 v = make_ushort2(L[key2][d], L[key2 + 1][d]);
    *(ushort2*)(dst + (size_t)d * kS + key2) = v;  // coalesced along keys
  }
}

// ---------------------------------------------------------------------------
// MFMA flash attention, S^T formulation, register-Q, pair-balanced.
// Round-4 restructure:
//  * XCD-group swizzle: 1D grid, all 16 pair-blocks of one (b,h) share
//    lin%8 -> same XCD; 8 groups x 512KB K+V = 4MB = one L2. Staging
//    becomes L2-hit instead of 8x-duplicated HBM fetch (257MB -> ~60MB).
//  * Double-buffered K AND V (40 KB LDS total, 4 blocks/CU exact fit):
//    K/V(kt+1) issued at iter TOP into the spare buffer -> full-iteration
//    (~2000 cy) latency cover; ONE __syncthreads per k-tile (its vmcnt(0)
//    drain is then free). Halves barrier count vs round-3.
//  * VALU trims: v_cvt_pk_bf16_f32 P-store, defer-max (T13, log2-thr 8,
//    P <= 256 safe in bf16/fp32), setprio around MFMA clusters (T5).
// ---------------------------------------------------------------------------
__global__ __launch_bounds__(256, 4) void flash_attn_mfma(
    unsigned short* __restrict__ qkvb, const unsigned short* __restrict__ vtb,
    const int* __restrict__ cflag) {
  __shared__ unsigned short QP[4096];     // Q then P buffer            8 KB
  __shared__ unsigned short Ks[2][4096];  // K double buffer           16 KB
  __shared__ unsigned short Vt[2][4096];  // V double buffer           16 KB

  // XCD-group decode: lin%8 = XCD slot; g = (b,h) group; all 16 pr of a
  // group have the same lin%8 -> co-located on one XCD's L2 (bijective).
  const int lin = blockIdx.x;
  const int pr = lin >> 6;                      // 0..15 (pair id)
  const int g  = ((lin >> 3) & 7) * 8 + (lin & 7);  // 0..63
  const int h = g & 15, b = g >> 4;
  const int t = threadIdx.x;
  const int lane = t & 63, l15 = lane & 15, quad = lane >> 4, w = t >> 6;
  const bool causal = (*cflag) != 0;

  unsigned short* qbase = qkvb + (size_t)(b * kS) * k3D + h * kDH;
  const unsigned short* vbase = vtb + (size_t)((b * kH + h) * kDH) * kS;
  const int c0 = t, c1 = t + 256;

  for (int half = 0; half < 2; ++half) {
    const int qt = half ? (31 - pr) : pr;
    const int q0 = qt * 64;
    const int ntiles = causal ? (qt + 1) : 32;

    // ---- prologue: stage Q + K0 + V0 (all into buffer 0)
    async16(qbase + (size_t)(q0 + (c0 & 63)) * k3D + (c0 >> 6) * 8, QP + c0 * 8);
    async16(qbase + (size_t)(q0 + (c1 & 63)) * k3D + (c1 >> 6) * 8, QP + c1 * 8);
    async16(qbase + kD + (size_t)(c0 & 63) * k3D + (c0 >> 6) * 8, Ks[0] + c0 * 8);
    async16(qbase + kD + (size_t)(c1 & 63) * k3D + (c1 >> 6) * 8, Ks[0] + c1 * 8);
    async16(vbase + (size_t)(c0 & 63) * kS + (c0 >> 6) * 8, Vt[0] + c0 * 8);
    async16(vbase + (size_t)(c1 & 63) * kS + (c1 >> 6) * 8, Vt[0] + c1 * 8);
    __syncthreads();  // drains Q + K0 + V0

    // hoist Q fragments to registers — QP becomes the P buffer afterwards
    // (QP is wave-private by row: reads/writes touch only rows w*16+l15)
    short8 bq[2];
#pragma unroll
    for (int kf = 0; kf < 2; ++kf)
      bq[kf] = *(const short8*)(
          QP + ((kf * 4 + quad) * 64 + w * 16 + l15) * 8);

    f32x4 O[4] = {};                  // [d-tile ntd]; q row = w*16+quad*4+i
    float m_i = -3.0e38f, l_i = 0.f;  // per q (q = w*16+l15)

    for (int kt = 0; kt < ntiles; ++kt) {
      const int cb = kt & 1, nb = cb ^ 1;
      const int kk0 = kt * 64;

      // ---- issue K/V(kt+1) into spare buffer: full-iteration cover
      if (kt + 1 < ntiles) {
        const int kn = kk0 + 64;
        async16(qbase + kD + (size_t)(kn + (c0 & 63)) * k3D + (c0 >> 6) * 8,
                Ks[nb] + c0 * 8);
        async16(qbase + kD + (size_t)(kn + (c1 & 63)) * k3D + (c1 >> 6) * 8,
                Ks[nb] + c1 * 8);
        async16(vbase + (size_t)(c0 & 63) * kS + kn + (c0 >> 6) * 8,
                Vt[nb] + c0 * 8);
        async16(vbase + (size_t)(c1 & 63) * kS + kn + (c1 >> 6) * 8,
                Vt[nb] + c1 * 8);
      }

      // ---- S^T = K·Q^T: key = kk0+mt*16+quad*4+reg, q = w*16+l15
      f32x4 s[4];
      __builtin_amdgcn_s_setprio(1);
#pragma unroll
      for (int mt = 0; mt < 4; ++mt) {
        short8 a0 = *(const short8*)(Ks[cb] + ((quad)*64 + mt * 16 + l15) * 8);
        short8 a1 =
            *(const short8*)(Ks[cb] + ((4 + quad) * 64 + mt * 16 + l15) * 8);
        f32x4 z = {};
        z = __builtin_amdgcn_mfma_f32_16x16x32_bf16(a0, bq[0], z, 0, 0, 0);
        z = __builtin_amdgcn_mfma_f32_16x16x32_bf16(a1, bq[1], z, 0, 0, 0);
        s[mt] = z;
      }
      __builtin_amdgcn_s_setprio(0);

      // ---- online softmax (scores in log2 domain; diagonal tile masked)
      const int gq = q0 + w * 16 + l15;
      if (causal && kt == ntiles - 1) {
#pragma unroll
        for (int mt = 0; mt < 4; ++mt)
#pragma unroll
          for (int i = 0; i < 4; ++i)
            if (kk0 + mt * 16 + quad * 4 + i > gq) s[mt][i] = -3.0e38f;
      }
      float mx = -3.0e38f;
#pragma unroll
      for (int mt = 0; mt < 4; ++mt)
#pragma unroll
        for (int i = 0; i < 4; ++i) mx = fmaxf(mx, s[mt][i]);
      mx = fmaxf(mx, __shfl_xor(mx, 16));
      mx = fmaxf(mx, __shfl_xor(mx, 32));

      // defer-max (T13): only rescale when the running max grew by > 8
      // (log2 domain -> P bounded by 2^8 = 256; fine in bf16/f32 accum).
      if (!__all(mx <= m_i + 8.0f)) {
        const float mn = fmaxf(m_i, mx);
        const float alpha = exp2v(m_i - mn);
        m_i = mn;
        l_i *= alpha;
#pragma unroll
        for (int i = 0; i < 4; ++i) {
          const float a = __shfl(alpha, quad * 4 + i);
#pragma unroll
          for (int ntd = 0; ntd < 4; ++ntd) O[ntd][i] *= a;
        }
      }

      float p[4][4];
      float rs = 0.f;
#pragma unroll
      for (int mt = 0; mt < 4; ++mt)
#pragma unroll
        for (int i = 0; i < 4; ++i) {
          p[mt][i] = exp2v(s[mt][i] - m_i);
          rs += p[mt][i];
        }
      rs += __shfl_xor(rs, 16);
      rs += __shfl_xor(rs, 32);
      l_i += rs;

      // packed P store via v_cvt_pk_bf16_f32: 4 consecutive keys at row gq
#pragma unroll
      for (int mt = 0; mt < 4; ++mt) {
        uint2 pk = make_uint2(cvtpk2bf(p[mt][0], p[mt][1]),
                              cvtpk2bf(p[mt][2], p[mt][3]));
        *(uint2*)(QP + ((mt * 2 + (quad >> 1)) * 64 + w * 16 + l15) * 8 +
                  (quad & 1) * 4) = pk;
      }

      // ---- O += P·V (P rows wave-private; compiler orders write->read)
      __builtin_amdgcn_s_setprio(1);
#pragma unroll
      for (int kf = 0; kf < 2; ++kf) {
        short8 aP = *(const short8*)(
            QP + ((kf * 4 + quad) * 64 + w * 16 + l15) * 8);
#pragma unroll
        for (int ntd = 0; ntd < 4; ++ntd) {
          short8 bV = *(const short8*)(
              Vt[cb] + ((kf * 4 + quad) * 64 + ntd * 16 + l15) * 8);
          O[ntd] = __builtin_amdgcn_mfma_f32_16x16x32_bf16(
              aP, bV, O[ntd], 0, 0, 0);
        }
      }
      __builtin_amdgcn_s_setprio(0);

      // single barrier per k-tile: (a) all reads of buffer cb complete ->
      // next iter may overwrite it; (b) vmcnt(0) drain covers K/V(kt+1),
      // which had the whole iteration to land.
      __syncthreads();
    }

    // ---- epilogue: /l, bf16, overwrite own Q slots
#pragma unroll
    for (int i = 0; i < 4; ++i) {
      const float linv = 1.0f / __shfl(l_i, quad * 4 + i);
      unsigned short* dst =
          qbase + (size_t)(q0 + w * 16 + quad * 4 + i) * k3D;
#pragma unroll
      for (int ntd = 0; ntd < 4; ++ntd)
        dst[ntd * 16 + l15] = f2bf(O[ntd][i] * linv);
    }
  }
}

// ---------------------------------------------------------------------------
extern "C" void kernel_launch(void* const* d_in, const int* in_sizes, int n_in,
                              void* d_out, int out_size, void* d_ws,
                              size_t ws_size, hipStream_t stream) {
  const float* x     = (const float*)d_in[0];
  const float* w_in  = (const float*)d_in[1];
  const float* b_in  = (const float*)d_in[2];
  const float* w_out = (const float*)d_in[3];
  const float* b_out = (const float*)d_in[4];
  const int*   cfl   = (const int*)d_in[5];
  float* out = (float*)d_out;

  // workspace layout (all 16B-aligned), total 92.3 MB
  char* ws = (char*)d_ws;
  unsigned short* qkvb = (unsigned short*)(ws);              // 8192x3072 bf16 = 48 MB
  unsigned short* xb   = (unsigned short*)(ws + 50331648);   // 8192x1024 bf16 = 16 MB
  unsigned short* wib  = (unsigned short*)(ws + 67108864);   // 3072x1024 bf16 =  6 MB
  unsigned short* wob  = (unsigned short*)(ws + 73400320);   // 1024x1024 bf16 =  2 MB
  unsigned short* vtb  = (unsigned short*)(ws + 75497472);   // [b,h,d,s] bf16 = 16 MB

  // 0) all three fp32->bf16 conversions in one launch
  cvt_bf16_3<<<(kM * kD + k3D * kD + kD * kD) / 4 / 256, 256, 0, stream>>>(
      x, w_in, w_out, xb, wib, wob);

  // 1) qkv = x @ w_in^T + b_in (bf16 out; Q cols pre-scaled by 0.125*log2e)
  //    256x256 tile, 512 threads: grid 12x32 = 384 blocks
  gemm_mfma<true, true><<<dim3(k3D / 256, kM / 256), 512, 0, stream>>>(
      xb, kD, wib, kD, b_in, qkvb, k3D, kD);

  // 2) V transpose for PV staging
  v_transpose<<<dim3(kS / 64, kH, kB), 256, 0, stream>>>(qkvb, vtb);

  // 3) flash attention (pair-balanced, XCD-grouped, double-buffered K/V)
  flash_attn_mfma<<<dim3(16 * kH * kB), 256, 0, stream>>>(qkvb, vtb, cfl);

  // 4) out = attn @ w_out^T + b_out (fp32 out; A rows inside qkvb, lda=3072)
  //    256x256 tile: grid 4x32 = 128 blocks
  gemm_mfma<false, false><<<dim3(kD / 256, kM / 256), 512, 0, stream>>>(
      qkvb, k3D, wob, kD, b_out, out, kD, kD);
}